// Round 13
// baseline (856.448 us; speedup 1.0000x reference)
//
#include <hip/hip_runtime.h>
#include <math.h>

// MRA attention, B=4 S=4096 H=768, 12 heads x 64, BLOCK=32, nb=128, top-512 blocks.
// Selection path f64; QKV projection + high-res sparse attention via split-bf16 MFMA.
// QKV GEMM: 3-product split as ONE K=2304 GEMM: [Xh|Xh|Xl]·[Wh|Wl|Wh]^T,
// z-outermost order; k-loop = 3-buffer depth-2 pipeline with counted vmcnt(4)
// + raw s_barrier (T4: no vmcnt(0) drain in the loop).

#define S_LEN 4096
#define NBLK  128
#define BHT   48
#define HD    64

typedef __attribute__((ext_vector_type(8))) short bf16x8;
typedef __attribute__((ext_vector_type(4))) float f32x4;
typedef unsigned short u16;
typedef unsigned int   u32;
typedef unsigned long long u64;

__device__ __forceinline__ u16 bf16rne(float x) {
    u32 u = __float_as_uint(x);
    u32 r = u + 0x7FFFu + ((u >> 16) & 1u);
    return (u16)(r >> 16);
}
__device__ __forceinline__ float b2f(u16 h) {
    return __uint_as_float((u32)h << 16);
}

__device__ __forceinline__ void gload_lds16(const void* g, void* l) {
    __builtin_amdgcn_global_load_lds((const __attribute__((address_space(1))) void*)g,
                                     (__attribute__((address_space(3))) void*)l, 16, 0, 0);
}

// ---------------------------------------------------------------------------
// 0) fused split: f32 -> bf16 hi/lo planes for X and all three W matrices.
// ---------------------------------------------------------------------------
#define NX8 (16384 * 768 / 8)
#define NW8 (768 * 768 / 8)

__global__ __launch_bounds__(256) void split_all(
    const float* __restrict__ X,
    const float* __restrict__ Wq, const float* __restrict__ Wk, const float* __restrict__ Wv,
    u16* __restrict__ Xh, u16* __restrict__ Xl,
    u16* __restrict__ Wh, u16* __restrict__ Wl)
{
    int i = blockIdx.x * 256 + threadIdx.x;
    if (i >= NX8 + 3 * NW8) return;
    const float* src; u16* dh; u16* dl; size_t off8;
    if (i < NX8) { src = X; dh = Xh; dl = Xl; off8 = i; }
    else {
        int j = i - NX8;
        int w = j / NW8, r = j - w * NW8;
        src = (w == 0) ? Wq : (w == 1) ? Wk : Wv;
        dh = Wh + (size_t)w * 768 * 768;
        dl = Wl + (size_t)w * 768 * 768;
        off8 = r;
    }
    const float4* xp = (const float4*)src + off8 * 2;
    float4 a = xp[0], b = xp[1];
    float xs[8] = {a.x, a.y, a.z, a.w, b.x, b.y, b.z, b.w};
    bf16x8 vh, vl;
    #pragma unroll
    for (int j = 0; j < 8; ++j) {
        u16 hh = bf16rne(xs[j]);
        float hf = b2f(hh);
        vh[j] = (short)hh;
        vl[j] = (short)bf16rne(xs[j] - hf);
    }
    *(bf16x8*)&dh[off8 * 8] = vh;
    *(bf16x8*)&dl[off8 * 8] = vl;
}

// ---------------------------------------------------------------------------
// 1) QKV projection: single K=2304 concat GEMM, BK=32, 3-buffer depth-2
//    pipeline (counted vmcnt + raw s_barrier).  128x128 tile, 4 waves.
// ---------------------------------------------------------------------------
__global__ __launch_bounds__(256, 3) void qkv_mfma(
    const u16* __restrict__ Xh, const u16* __restrict__ Xl,
    const u16* __restrict__ Wh, const u16* __restrict__ Wl,   // [3][768][768]
    const float* __restrict__ bq, const float* __restrict__ bk, const float* __restrict__ bv,
    const float* __restrict__ am,
    u16* __restrict__ Qh, u16* __restrict__ Ql,
    u16* __restrict__ Kh, u16* __restrict__ Kl,
    u16* __restrict__ Vth, u16* __restrict__ Vtl)
{
    const int wg = blockIdx.x;                       // 2304 = 3 z x 128 mt x 6 nt
    const int logical = (wg & 7) * 288 + (wg >> 3);  // XCD-chunked (2304 % 8 == 0)
    const int z   = logical / 768;                   // z outermost: one W set per L2 window
    const int idx = logical - z * 768;
    const int mt  = idx / 6;
    const int nt  = idx - mt * 6;

    const float* bias = (z == 0) ? bq : (z == 1) ? bk : bv;
    const u16* Wzh = Wh + (size_t)z * 768 * 768;
    const u16* Wzl = Wl + (size_t)z * 768 * 768;
    const int m0 = mt * 128, n0 = nt * 128;

    __shared__ char smem[49152];     // 3 x 16KB buffers: [A 8KB | B 8KB] each
    const int tid  = threadIdx.x;
    const int lane = tid & 63;
    const int w    = tid >> 6;                    // 4 waves, 2m x 2n
    const int wm   = (w >> 1) * 64, wn = (w & 1) * 64;

    const int rbase = (w < 2) ? m0 : n0;
    const int sub0  = (w & 1) * 4;                // which 4 row-subtiles this wave stages
    const int srow = lane >> 2;                       // 0..15
    const int scg  = (lane & 3) ^ ((lane >> 3) & 3);  // 0..3 (16B colgroup)
    const int tslot = (lane & 15) * 4 + ((lane >> 4) ^ ((lane >> 1) & 3));

    f32x4 acc[4][4];
    #pragma unroll
    for (int i = 0; i < 4; ++i)
        #pragma unroll
        for (int j = 0; j < 4; ++j) acc[i][j] = (f32x4){0.f, 0.f, 0.f, 0.f};

    auto STAGE = [&](int buf, int t) {               // 4 gload_lds per wave
        const int k0 = t * 32;
        const u16* srcA = (k0 < 1536) ? Xh : Xl;
        const u16* srcB = (k0 < 768) ? Wzh : ((k0 < 1536) ? Wzl : Wzh);
        const int  kk   = (k0 < 768) ? k0 : ((k0 < 1536) ? (k0 - 768) : (k0 - 1536));
        const u16* src  = (w < 2) ? srcA : srcB;
        char* dst = smem + buf * 16384 + ((w < 2) ? 0 : 8192);
        #pragma unroll
        for (int i = 0; i < 4; ++i) {
            const u16* g = src + (size_t)(rbase + (sub0 + i) * 16 + srow) * 768 + (kk + scg * 8);
            gload_lds16(g, dst + (sub0 + i) * 1024);
        }
    };

    STAGE(0, 0);
    STAGE(1, 1);                      // depth-2: two tiles in flight
    int cb = 0;                       // buffer of tile t
    for (int t = 0; t < 72; ++t) {
        if (t == 71) { asm volatile("s_waitcnt vmcnt(0)" ::: "memory"); }
        else         { asm volatile("s_waitcnt vmcnt(4)" ::: "memory"); }  // tile t landed (mine)
        __builtin_amdgcn_s_barrier();                 // all waves' tile-t loads landed
        __builtin_amdgcn_sched_barrier(0);            // pin: no hoisting across barrier
        if (t + 2 < 72) {
            int sb = (cb + 2 >= 3) ? (cb - 1) : (cb + 2);   // (t+2) % 3
            STAGE(sb, t + 2);                                // readers done (passed barrier)
        }
        const char* bufp = smem + cb * 16384;
        bf16x8 af[4], bf[4];
        #pragma unroll
        for (int f = 0; f < 4; ++f) {
            af[f] = *(const bf16x8*)&bufp[((w >> 1) * 4 + f) * 1024 + tslot * 16];
            bf[f] = *(const bf16x8*)&bufp[8192 + ((w & 1) * 4 + f) * 1024 + tslot * 16];
        }
        #pragma unroll
        for (int i = 0; i < 4; ++i)
            #pragma unroll
            for (int j = 0; j < 4; ++j)
                acc[i][j] = __builtin_amdgcn_mfma_f32_16x16x32_bf16(af[i], bf[j], acc[i][j], 0, 0, 0);
        cb = (cb == 2) ? 0 : (cb + 1);
    }
    __syncthreads();                  // epilogue reuses smem

    // epilogue: C/D layout col=lane&15, row=(lane>>4)*4+reg
    if (z < 2) {
        u16* Ph = (z == 0) ? Qh : Kh;
        u16* Pl = (z == 0) ? Ql : Kl;
        const float qscale = (z == 0) ? 0.125f : 1.0f;
        #pragma unroll
        for (int i = 0; i < 4; ++i) {
            #pragma unroll
            for (int j = 0; j < 4; ++j) {
                int col = n0 + wn + j * 16 + (lane & 15);
                int h = col >> 6, d = col & 63;
                float bsv = bias[col];
                #pragma unroll
                for (int r = 0; r < 4; ++r) {
                    int row = m0 + wm + i * 16 + (lane >> 4) * 4 + r;
                    int b = row >> 12, s = row & 4095;
                    float mv = 1.0f + am[row] * 1e-4f;
                    float e = (acc[i][j][r] + bsv) * mv * qscale;
                    u16 hh = bf16rne(e);
                    u16 ll = bf16rne(e - b2f(hh));
                    size_t a = (((size_t)(b * 12 + h)) * S_LEN + s) * HD + d;
                    Ph[a] = hh; Pl[a] = ll;
                }
            }
        }
    } else {
        // V: transpose to [bh][d][s], 4 passes of 64d x 64s through LDS
        u32* buf = (u32*)smem;           // [64][66]
        const int bb = m0 >> 12;
        #pragma unroll
        for (int p = 0; p < 4; ++p) {
            const int hh_ = p & 1;       // head half (col half)
            const int rh  = p >> 1;      // row half
            __syncthreads();
            if (((w & 1) == hh_) && ((w >> 1) == rh)) {
                #pragma unroll
                for (int i = 0; i < 4; ++i) {
                    #pragma unroll
                    for (int j = 0; j < 4; ++j) {
                        int d_local = j * 16 + (lane & 15);
                        int col = n0 + hh_ * 64 + d_local;
                        float bsv = bias[col];
                        #pragma unroll
                        for (int r = 0; r < 4; ++r) {
                            int s_local = i * 16 + (lane >> 4) * 4 + r;
                            float mv = 1.0f + am[m0 + rh * 64 + s_local] * 1e-4f;
                            float e = (acc[i][j][r] + bsv) * mv;
                            u16 h16 = bf16rne(e);
                            u16 l16 = bf16rne(e - b2f(h16));
                            buf[d_local * 66 + s_local] = ((u32)h16 << 16) | (u32)l16;
                        }
                    }
                }
            }
            __syncthreads();
            int d_local = tid >> 2;
            int s_chunk = (tid & 3) * 16;
            int head = (n0 >> 6) + hh_;
            size_t ob = (((size_t)(bb * 12 + head)) * HD + d_local) * S_LEN
                        + (m0 & 4095) + rh * 64 + s_chunk;
            #pragma unroll
            for (int gq = 0; gq < 2; ++gq) {
                bf16x8 vh8, vl8;
                #pragma unroll
                for (int t = 0; t < 8; ++t) {
                    u32 pk = buf[d_local * 66 + s_chunk + gq * 8 + t];
                    vh8[t] = (short)(pk >> 16);
                    vl8[t] = (short)(pk & 0xFFFF);
                }
                *(bf16x8*)&Vth[ob + gq * 8] = vh8;
                *(bf16x8*)&Vtl[ob + gq * 8] = vl8;
            }
        }
    }
}

// ---------------------------------------------------------------------------
// 2) f64 selection path: mask-weighted block sums of hidden states.
// ---------------------------------------------------------------------------
__global__ __launch_bounds__(256) void hsum_kernel(
    const float* __restrict__ X, const float* __restrict__ am,
    double* __restrict__ hsum, double* __restrict__ tcd)
{
    int blk = blockIdx.x & 127, b = blockIdx.x >> 7;
    int tid = threadIdx.x;
    const float* xb  = X  + ((size_t)(b * S_LEN + blk * 32)) * 768;
    const float* amb = am + b * S_LEN + blk * 32;
    for (int d = tid; d < 768; d += 256) {
        double s = 0.0;
        for (int t = 0; t < 32; ++t)
            s += (double)xb[(size_t)t * 768 + d] * (1.0 + (double)amb[t] * 1e-4);
        hsum[(size_t)blockIdx.x * 768 + d] = s;
    }
    if (tid == 0) {
        double t = 0.0;
        for (int i = 0; i < 32; ++i) t += 1.0 + (double)amb[i] * 1e-4;
        tcd[blockIdx.x] = t;
    }
}

// ---------------------------------------------------------------------------
// 3) qhat/khat (f64)
// ---------------------------------------------------------------------------
__global__ __launch_bounds__(256) void ghat_kernel(
    const double* __restrict__ hsum,
    const float* __restrict__ Wq, const float* __restrict__ Wk,
    const float* __restrict__ bq, const float* __restrict__ bk,
    const double* __restrict__ tcd,
    double* __restrict__ qhat, double* __restrict__ khat)
{
    const float* W; const float* bias; double* outp;
    if (blockIdx.z == 0) { W = Wq; bias = bq; outp = qhat; }
    else                 { W = Wk; bias = bk; outp = khat; }
    const int n0 = blockIdx.x * 64, m0 = blockIdx.y * 64;
    __shared__ double As[16][72];
    __shared__ float  Bs[16][72];
    const int tid = threadIdx.x;
    const int tx = tid & 15, ty = tid >> 4;
    double acc[4][4] = {};
    const int lr = tid >> 2, lc = (tid & 3) * 4;
    for (int k0 = 0; k0 < 768; k0 += 16) {
        double a0 = hsum[(size_t)(m0 + lr) * 768 + k0 + lc + 0];
        double a1 = hsum[(size_t)(m0 + lr) * 768 + k0 + lc + 1];
        double a2 = hsum[(size_t)(m0 + lr) * 768 + k0 + lc + 2];
        double a3 = hsum[(size_t)(m0 + lr) * 768 + k0 + lc + 3];
        float4 bv = *(const float4*)&W[(size_t)(n0 + lr) * 768 + k0 + lc];
        __syncthreads();
        As[lc+0][lr] = a0; As[lc+1][lr] = a1; As[lc+2][lr] = a2; As[lc+3][lr] = a3;
        Bs[lc+0][lr] = bv.x; Bs[lc+1][lr] = bv.y; Bs[lc+2][lr] = bv.z; Bs[lc+3][lr] = bv.w;
        __syncthreads();
        #pragma unroll
        for (int kk = 0; kk < 16; ++kk) {
            double af[4]; float bf[4];
            #pragma unroll
            for (int i = 0; i < 4; ++i) af[i] = As[kk][ty*4+i];
            #pragma unroll
            for (int j = 0; j < 4; ++j) bf[j] = Bs[kk][tx*4+j];
            #pragma unroll
            for (int i = 0; i < 4; ++i)
                #pragma unroll
                for (int j = 0; j < 4; ++j)
                    acc[i][j] += af[i] * (double)bf[j];
        }
    }
    #pragma unroll
    for (int i = 0; i < 4; ++i) {
        int m = m0 + ty*4 + i;
        int b = m >> 7, blk = m & 127;
        double t = tcd[m];
        #pragma unroll
        for (int j = 0; j < 4; ++j) {
            int o = n0 + tx*4 + j;
            int h = o >> 6, d = o & 63;
            outp[(((size_t)(b*12 + h)) * NBLK + blk) * HD + d] = (acc[i][j] + t * (double)bias[o]) / (t + 1e-6);
        }
    }
}

// ---------------------------------------------------------------------------
// 4) low-res logits (f64), 4 query rows per block, fused u64 selection keys.
// ---------------------------------------------------------------------------
__global__ __launch_bounds__(128) void lrl_kernel(
    const double* __restrict__ qhat, const double* __restrict__ khat,
    const double* __restrict__ tcd,
    double* __restrict__ lrl, double* __restrict__ rmax,
    u64* __restrict__ keys)
{
    const int q0 = blockIdx.x * 4, bh = blockIdx.y;
    const int b = bh / 12;
    __shared__ double qr[4][64];
    __shared__ double red[4][128];
    const int tid = threadIdx.x;
    if (tid < 64) {
        #pragma unroll
        for (int qq = 0; qq < 4; ++qq)
            qr[qq][tid] = qhat[(((size_t)bh) * NBLK + q0 + qq) * HD + tid];
    }
    __syncthreads();
    const double* kr = &khat[(((size_t)bh) * NBLK + tid) * HD];
    double s[4] = {0.0, 0.0, 0.0, 0.0};
    for (int d = 0; d < 64; d += 2) {
        double2 kv2 = *(const double2*)&kr[d];
        #pragma unroll
        for (int qq = 0; qq < 4; ++qq)
            s[qq] += qr[qq][d] * kv2.x + qr[qq][d + 1] * kv2.y;
    }
    #pragma unroll
    for (int qq = 0; qq < 4; ++qq) { s[qq] *= 0.125; red[qq][tid] = s[qq]; }
    __syncthreads();
    for (int off = 64; off > 0; off >>= 1) {
        if (tid < off) {
            #pragma unroll
            for (int qq = 0; qq < 4; ++qq)
                red[qq][tid] = fmax(red[qq][tid], red[qq][tid + off]);
        }
        __syncthreads();
    }
    const double tck = tcd[b * NBLK + tid];
    #pragma unroll
    for (int qq = 0; qq < 4; ++qq) {
        const int qi = q0 + qq;
        const double rmaxv = red[qq][0];
        double pen = (tcd[b * NBLK + qi] * tck < 0.5) ? 1e4 : 0.0;
        const double lv = s[qq] - pen;
        lrl[(size_t)bh * (NBLK*NBLK) + (size_t)qi * NBLK + tid] = lv;
        if (tid == 0) rmax[bh * NBLK + qi] = rmaxv;
        int dd = qi - tid; if (dd < 0) dd = -dd;
        double ks_ = lv - rmaxv + ((dd <= 1) ? 5000.0 : 0.0);
        u64 u = (u64)__double_as_longlong(ks_);
        u = (u >> 63) ? ~u : (u | 0x8000000000000000ULL);
        keys[(size_t)bh * (NBLK*NBLK) + (size_t)qi * NBLK + tid] = u;
    }
}

// ---------------------------------------------------------------------------
// 5) v_hat (f32) + tc (from hsum's f64 tcd).
// ---------------------------------------------------------------------------
__global__ __launch_bounds__(64) void vhat_kernel(
    const u16* __restrict__ Vth, const u16* __restrict__ Vtl,
    const double* __restrict__ tcd,
    float* __restrict__ vhat, float* __restrict__ tcf)
{
    const int d = blockIdx.x, bh = blockIdx.y;
    const int b = bh / 12;
    const int l = threadIdx.x;
    const u16* ph = Vth + ((size_t)bh * HD + d) * S_LEN + l * 64;
    const u16* pl = Vtl + ((size_t)bh * HD + d) * S_LEN + l * 64;
    float s[2] = {0.f, 0.f};
    #pragma unroll
    for (int g = 0; g < 2; ++g) {
        #pragma unroll
        for (int v = 0; v < 4; ++v) {
            bf16x8 vh = *(const bf16x8*)&ph[g * 32 + v * 8];
            bf16x8 vl = *(const bf16x8*)&pl[g * 32 + v * 8];
            #pragma unroll
            for (int j = 0; j < 8; ++j)
                s[g] += b2f((u16)vh[j]) + b2f((u16)vl[j]);
        }
    }
    #pragma unroll
    for (int g = 0; g < 2; ++g) {
        int blk = l * 2 + g;
        float tc = (float)tcd[b * NBLK + blk];
        vhat[(((size_t)bh) * NBLK + blk) * HD + d] = s[g] / (tc + 1e-6f);
        if (d == 0) tcf[bh * NBLK + blk] = tc;
    }
}

// ---------------------------------------------------------------------------
// 6) top-512 radix select (per-wave privatized histograms) + per-row lists.
// ---------------------------------------------------------------------------
__global__ __launch_bounds__(256) void topk_kernel(
    const u64* __restrict__ keys,
    double* __restrict__ th64, int* __restrict__ cnt, unsigned char* __restrict__ lists,
    int* __restrict__ eqbuf, int* __restrict__ eqcnt)
{
    const int bh = blockIdx.x, tid = threadIdx.x;
    const int wid = tid >> 6;
    __shared__ int hist[4][256];
    __shared__ u64 s_pref;
    __shared__ int s_K;
    const u64* kp = keys + (size_t)bh * (NBLK*NBLK);
    if (tid < 128) cnt[bh * NBLK + tid] = 0;
    if (tid == 0) eqcnt[bh] = 0;

    u64 pref = 0, pmask = 0;
    int K = 512;
    for (int by = 7; by >= 0; --by) {
        #pragma unroll
        for (int w = 0; w < 4; ++w) hist[w][tid] = 0;
        __syncthreads();
        for (int i = tid; i < NBLK*NBLK; i += 256) {
            u64 u = kp[i];
            if ((u & pmask) == pref)
                atomicAdd(&hist[wid][(int)((u >> (by*8)) & 255)], 1);
        }
        __syncthreads();
        int tot = hist[0][tid] + hist[1][tid] + hist[2][tid] + hist[3][tid];
        hist[0][tid] = tot;
        __syncthreads();
        if (tid == 0) {
            int c = 0, bsel = 0;
            for (int x = 255; x >= 0; --x) {
                if (c + hist[0][x] >= K) { bsel = x; break; }
                c += hist[0][x];
            }
            s_pref = pref | ((u64)bsel << (by*8));
            s_K = K - c;
        }
        __syncthreads();
        pref = s_pref; K = s_K;
        pmask |= 0xFFULL << (by*8);
        __syncthreads();
    }
    const u64 tkey = pref;
    int n_take = K;
    if (tid == 0) {
        u64 u = (tkey & 0x8000000000000000ULL) ? (tkey ^ 0x8000000000000000ULL) : ~tkey;
        th64[bh] = __longlong_as_double((long long)u);
    }
    for (int i = tid; i < NBLK*NBLK; i += 256) {
        u64 u = kp[i];
        if (u > tkey) {
            int qi = i >> 7, ki = i & 127;
            int pos = atomicAdd(&cnt[bh * NBLK + qi], 1);
            lists[(((size_t)bh) * NBLK + qi) * NBLK + pos] = (unsigned char)ki;
        } else if (u == tkey) {
            int e = atomicAdd(&eqcnt[bh], 1);
            if (e < 512) eqbuf[bh * 512 + e] = i;
        }
    }
    __syncthreads();
    if (tid == 0) {
        int ne = eqcnt[bh]; if (ne > 512) ne = 512;
        int* eb = &eqbuf[bh * 512];
        for (int a = 1; a < ne; ++a) {
            int v = eb[a]; int x = a - 1;
            while (x >= 0 && eb[x] > v) { eb[x+1] = eb[x]; --x; }
            eb[x+1] = v;
        }
        if (n_take > ne) n_take = ne;
        for (int j = 0; j < n_take; ++j) {
            int i = eb[j]; int qi = i >> 7, ki = i & 127;
            int pos = cnt[bh * NBLK + qi]++;
            lists[(((size_t)bh) * NBLK + qi) * NBLK + pos] = (unsigned char)ki;
        }
    }
    __syncthreads();
    if (tid < 128) {
        int n = cnt[bh * NBLK + tid];
        unsigned char* l = &lists[(((size_t)bh) * NBLK + tid) * NBLK];
        for (int a = 1; a < n; ++a) {
            unsigned char v = l[a]; int x = a - 1;
            while (x >= 0 && l[x] > v) { l[x+1] = l[x]; --x; }
            l[x+1] = v;
        }
    }
}

// ---------------------------------------------------------------------------
// 7) High-res sparse attention: split-bf16 MFMA, vote-gated defer-max softmax,
//    P double-buffer -> 1 barrier/iter.  One wave per (bh, qi).
// ---------------------------------------------------------------------------
__global__ __launch_bounds__(64) void hr_mfma(
    const u16* __restrict__ Qh, const u16* __restrict__ Ql,
    const u16* __restrict__ Kh, const u16* __restrict__ Kl,
    const u16* __restrict__ Vth, const u16* __restrict__ Vtl,
    const double* __restrict__ lrl64, const double* __restrict__ rmax64, const double* __restrict__ th64,
    const int* __restrict__ cnt, const unsigned char* __restrict__ lists,
    const float* __restrict__ vhat, const float* __restrict__ tcf,
    const float* __restrict__ am, float* __restrict__ out)
{
    const int qi = blockIdx.x, bh = blockIdx.y;
    const int l  = threadIdx.x;
    const int lr_ = l & 15, lg = l >> 4;
    __shared__ u16 PhL[2][32][40];    // double-buffered P tiles
    __shared__ u16 PlL[2][32][40];
    __shared__ float wlr[128];
    __shared__ float lrvec[64];

    bf16x8 qfh[2][2], qfl[2][2];
    #pragma unroll
    for (int qs = 0; qs < 2; ++qs)
        #pragma unroll
        for (int ds = 0; ds < 2; ++ds) {
            size_t a = (((size_t)bh) * S_LEN + qi * 32 + qs * 16 + lr_) * HD + ds * 32 + lg * 8;
            qfh[qs][ds] = *(const bf16x8*)&Qh[a];
            qfl[qs][ds] = *(const bf16x8*)&Ql[a];
        }

    float m_run[2][4], l_part[2][4];
    f32x4 oacc[2][4];
    #pragma unroll
    for (int qs = 0; qs < 2; ++qs) {
        #pragma unroll
        for (int r = 0; r < 4; ++r) { m_run[qs][r] = -1e30f; l_part[qs][r] = 0.f; }
        #pragma unroll
        for (int dv = 0; dv < 4; ++dv) oacc[qs][dv] = (f32x4){0.f, 0.f, 0.f, 0.f};
    }

    const int c = cnt[bh * NBLK + qi];
    const unsigned char* ml = &lists[(((size_t)bh) * NBLK + qi) * NBLK];

    int pb = 0;
    for (int bi = 0; bi < c; ++bi) {
        const int ki = ml[bi];
        f32x4 S[2][2];
        #pragma unroll
        for (int qs = 0; qs < 2; ++qs)
            #pragma unroll
            for (int ks = 0; ks < 2; ++ks) S[qs][ks] = (f32x4){0.f, 0.f, 0.f, 0.f};
        #pragma unroll
        for (int ds = 0; ds < 2; ++ds)
            #pragma unroll
            for (int ks = 0; ks < 2; ++ks) {
                size_t a = (((size_t)bh) * S_LEN + ki * 32 + ks * 16 + lr_) * HD + ds * 32 + lg * 8;
                bf16x8 kh = *(const bf16x8*)&Kh[a];
                bf16x8 kl = *(const bf16x8*)&Kl[a];
                S[0][ks] = __builtin_amdgcn_mfma_f32_16x16x32_bf16(qfh[0][ds], kh, S[0][ks], 0, 0, 0);
                S[1][ks] = __builtin_amdgcn_mfma_f32_16x16x32_bf16(qfh[1][ds], kh, S[1][ks], 0, 0, 0);
                S[0][ks] = __builtin_amdgcn_mfma_f32_16x16x32_bf16(qfh[0][ds], kl, S[0][ks], 0, 0, 0);
                S[1][ks] = __builtin_amdgcn_mfma_f32_16x16x32_bf16(qfh[1][ds], kl, S[1][ks], 0, 0, 0);
                S[0][ks] = __builtin_amdgcn_mfma_f32_16x16x32_bf16(qfl[0][ds], kh, S[0][ks], 0, 0, 0);
                S[1][ks] = __builtin_amdgcn_mfma_f32_16x16x32_bf16(qfl[1][ds], kh, S[1][ks], 0, 0, 0);
            }
        // vote-gated defer-max (exact for mask==1: combine invariant to lagged m)
        float lmax[2][4];
        bool need = false;
        #pragma unroll
        for (int qs = 0; qs < 2; ++qs)
            #pragma unroll
            for (int r = 0; r < 4; ++r) {
                lmax[qs][r] = fmaxf(S[qs][0][r], S[qs][1][r]);
                need |= (lmax[qs][r] > m_run[qs][r] + 8.f);
            }
        if (__any(need)) {   // rare: full per-row max reduce + rescale
            #pragma unroll
            for (int qs = 0; qs < 2; ++qs)
                #pragma unroll
                for (int r = 0; r < 4; ++r) {
                    float bm = lmax[qs][r];
                    bm = fmaxf(bm, __shfl_xor(bm, 1));
                    bm = fmaxf(bm, __shfl_xor(bm, 2));
                    bm = fmaxf(bm, __shfl_xor(bm, 4));
                    bm = fmaxf(bm, __shfl_xor(bm, 8));
                    float mn = fmaxf(m_run[qs][r], bm);
                    float sc = __expf(m_run[qs][r] - mn);
                    m_run[qs][r] = mn;
                    l_part[qs][r] *= sc;
                    #pragma unroll
                    for (int dv = 0; dv < 4; ++dv) oacc[qs][dv][r] *= sc;
                }
        }
        #pragma unroll
        for (int qs = 0; qs < 2; ++qs)
            #pragma unroll
            for (int r = 0; r < 4; ++r) {
                float p0 = __expf(S[qs][0][r] - m_run[qs][r]);
                float p1 = __expf(S[qs][1][r] - m_run[qs][r]);
                l_part[qs][r] += p0 + p1;          // per-lane partial; reduced after loop
                int row = qs * 16 + lg * 4 + r;
                u16 h0 = bf16rne(p0); u16 lo0 = bf16rne(p0 - b2f(h0));
                u16 h1 = bf16rne(p1); u16 lo1 = bf16rne(p1 - b2f(h1));
                PhL[pb][row][lr_]      = h0;  PlL[pb][row][lr_]      = lo0;
                PhL[pb][row][16 + lr_] = h1;  PlL[pb][row][16 + lr_] = lo1;
            }
        __syncthreads();   // P[pb] visible; previous buffer's readers already passed here
        bf16x8 pah[2], pal[2];
        #pragma unroll
        for (int qs = 0; qs < 2; ++qs) {
            pah[qs] = *(const bf16x8*)&PhL[pb][qs * 16 + lr_][lg * 8];
            pal[qs] = *(const bf16x8*)&PlL[pb][qs * 16 + lr_][lg * 8];
        }
        #pragma unroll
        for (int dv = 0; dv < 4; ++dv) {
            size_t a = (((size_t)bh) * HD + dv * 16 + lr_) * S_LEN + ki * 32 + lg * 8;
            bf16x8 vh = *(const bf16x8*)&Vth[a];
            bf16x8 vl = *(const bf16x8*)&Vtl[a];
            #pragma unroll
            for (int qs = 0; qs < 2; ++qs) {
                oacc[qs][dv] = __builtin_amdgcn_mfma_f32_16x16x32_bf16(pah[qs], vh, oacc[qs][dv], 0, 0, 0);
                oacc[qs][dv] = __builtin_amdgcn_mfma_f32_16x16x32_bf16(pah[qs], vl, oacc[qs][dv], 0, 0, 0);
                oacc[qs][dv] = __builtin_amdgcn_mfma_f32_16x16x32_bf16(pal[qs], vh, oacc[qs][dv], 0, 0, 0);
            }
        }
        pb ^= 1;           // no trailing barrier: next iter writes the other buffer
    }
    __syncthreads();

    // final l reduction (once): sum l_part across the 16 k-lanes of each row
    float l_run[2][4];
    #pragma unroll
    for (int qs = 0; qs < 2; ++qs)
        #pragma unroll
        for (int r = 0; r < 4; ++r) {
            float rs = l_part[qs][r];
            rs += __shfl_xor(rs, 1);
            rs += __shfl_xor(rs, 2);
            rs += __shfl_xor(rs, 4);
            rs += __shfl_xor(rs, 8);
            l_run[qs][r] = rs;
        }

    // ---- low-res branch ----
    const double thv  = th64[bh];
    const double rm64 = rmax64[bh * NBLK + qi];
    const int b = bh / 12, h = bh % 12;
    float wpair = 0.f;
    #pragma unroll
    for (int half = 0; half < 2; ++half) {
        int m = l + half * 64;
        double lv = lrl64[(size_t)bh * (NBLK*NBLK) + (size_t)qi * NBLK + m];
        int dd = qi - m; if (dd < 0) dd = -dd;
        double s = lv - rm64 + ((dd <= 1) ? 5000.0 : 0.0);
        float wv;
        if (s >= thv) wv = 0.f;
        else          wv = (float)exp(lv - rm64) * tcf[bh * NBLK + m];
        wlr[m] = wv;
        wpair += wv;
    }
    float s_lrn = wpair;
    s_lrn += __shfl_xor(s_lrn, 1);
    s_lrn += __shfl_xor(s_lrn, 2);
    s_lrn += __shfl_xor(s_lrn, 4);
    s_lrn += __shfl_xor(s_lrn, 8);
    s_lrn += __shfl_xor(s_lrn, 16);
    s_lrn += __shfl_xor(s_lrn, 32);
    __syncthreads();
    float a_ = 0.f;
    for (int m = 0; m < 128; ++m)
        a_ += wlr[m] * vhat[(((size_t)bh) * NBLK + m) * HD + l];
    lrvec[l] = a_;
    __syncthreads();
    float lv4[4];
    #pragma unroll
    for (int dv = 0; dv < 4; ++dv) lv4[dv] = lrvec[dv * 16 + lr_];

    // ---- combine & write ----
    const float rmf = (float)rm64;
    #pragma unroll
    for (int qs = 0; qs < 2; ++qs)
        #pragma unroll
        for (int r = 0; r < 4; ++r) {
            int q = qs * 16 + lg * 4 + r;
            int srow = qi * 32 + q;
            float mv = 1.0f + am[b * S_LEN + srow] * 1e-4f;
            float logc = (rmf - m_run[qs][r]) * mv;
            float lrc = (logc <= 0.f) ? expf(logc)  : 1.0f;
            float hrc = (logc >  0.f) ? expf(-logc) : 1.0f;
            float den = l_run[qs][r] * hrc + s_lrn * lrc + 1e-6f;
            float scd = mv / den;
            size_t ob = ((size_t)(b * S_LEN + srow)) * 768 + h * HD;
            #pragma unroll
            for (int dv = 0; dv < 4; ++dv)
                out[ob + dv * 16 + lr_] = (oacc[qs][dv][r] * hrc + lv4[dv] * lrc) * scd;
        }
}

// ---------------------------------------------------------------------------
extern "C" void kernel_launch(void* const* d_in, const int* in_sizes, int n_in,
                              void* d_out, int out_size, void* d_ws, size_t ws_size,
                              hipStream_t stream)
{
    (void)in_sizes; (void)n_in; (void)out_size; (void)ws_size;
    const float* X  = (const float*)d_in[0];
    const float* am = (const float*)d_in[1];
    const float* Wq = (const float*)d_in[2];
    const float* bq = (const float*)d_in[3];
    const float* Wk = (const float*)d_in[4];
    const float* bk = (const float*)d_in[5];
    const float* Wv = (const float*)d_in[6];
    const float* bv = (const float*)d_in[7];
    float* out = (float*)d_out;

    char* p = (char*)d_ws;
    const size_t PLANE = (size_t)BHT * S_LEN * HD * 2;
    u16* Qh  = (u16*)p; p += PLANE;
    u16* Ql  = (u16*)p; p += PLANE;
    u16* Kh  = (u16*)p; p += PLANE;
    u16* Kl  = (u16*)p; p += PLANE;
    u16* Vth = (u16*)p; p += PLANE;
    u16* Vtl = (u16*)p; p += PLANE;
    char* region = p;

    // ---- phase A layout (dead after qkv_mfma): bf16 splits of X, W ----
    char* pa = region;
    u16* Xh = (u16*)pa; pa += (size_t)16384 * 768 * 2;
    u16* Xl = (u16*)pa; pa += (size_t)16384 * 768 * 2;
    u16* Wh = (u16*)pa; pa += (size_t)3 * 768 * 768 * 2;
    u16* Wl = (u16*)pa; pa += (size_t)3 * 768 * 768 * 2;

    // ---- phase B/C layout (reuses phase A region) ----
    char* pb = region;
    double* hsum   = (double*)pb; pb += (size_t)512 * 768 * 8;
    double* tcd    = (double*)pb; pb += (size_t)512 * 8;
    double* qhat64 = (double*)pb; pb += (size_t)BHT * NBLK * HD * 8;
    double* khat64 = (double*)pb; pb += (size_t)BHT * NBLK * HD * 8;
    double* lrl64  = (double*)pb; pb += (size_t)BHT * NBLK * NBLK * 8;
    double* rmax64 = (double*)pb; pb += (size_t)BHT * NBLK * 8;
    double* th64   = (double*)pb; pb += (size_t)BHT * 8;
    u64* keys   = (u64*)pb;   pb += (size_t)BHT * NBLK * NBLK * 8;
    float* vhat = (float*)pb; pb += (size_t)BHT * NBLK * HD * 4;
    float* tcf  = (float*)pb; pb += (size_t)BHT * NBLK * 4;
    int* cnt    = (int*)pb;   pb += (size_t)BHT * NBLK * 4;
    int* eqbuf  = (int*)pb;   pb += (size_t)BHT * 512 * 4;
    int* eqcnt  = (int*)pb;   pb += (size_t)BHT * 4;
    unsigned char* lists = (unsigned char*)pb; pb += (size_t)BHT * NBLK * NBLK;

    // phase A: fused split + MFMA QKV projection -> bf16 planes
    split_all<<<7008, 256, 0, stream>>>(X, Wq, Wk, Wv, Xh, Xl, Wh, Wl);
    qkv_mfma<<<2304, 256, 0, stream>>>(Xh, Xl, Wh, Wl, bq, bk, bv, am,
                                       Qh, Ql, Kh, Kl, Vth, Vtl);

    // phase B: f64 selection path (region reused — stream order serializes)
    hsum_kernel<<<512, 256, 0, stream>>>(X, am, hsum, tcd);
    ghat_kernel<<<dim3(12, 8, 2), 256, 0, stream>>>(hsum, Wq, Wk, bq, bk, tcd, qhat64, khat64);
    lrl_kernel<<<dim3(32, BHT), 128, 0, stream>>>(qhat64, khat64, tcd, lrl64, rmax64, keys);
    vhat_kernel<<<dim3(64, BHT), 64, 0, stream>>>(Vth, Vtl, tcd, vhat, tcf);
    topk_kernel<<<BHT, 256, 0, stream>>>(keys, th64, cnt, lists, eqbuf, eqcnt);

    // phase C: high-res + combine
    hr_mfma<<<dim3(NBLK, BHT), 64, 0, stream>>>(Qh, Ql, Kh, Kl, Vth, Vtl,
                                                lrl64, rmax64, th64,
                                                cnt, lists, vhat, tcf, am, out);
}

// Round 14
// 637.643 us; speedup vs baseline: 1.3431x; 1.3431x over previous
//
#include <hip/hip_runtime.h>
#include <math.h>

// MRA attention, B=4 S=4096 H=768, 12 heads x 64, BLOCK=32, nb=128, top-512 blocks.
// Selection path f64; QKV projection + high-res sparse attention via split-bf16 MFMA.
// QKV GEMM: 3-product split as ONE K=2304 GEMM: [Xh|Xh|Xl]·[Wh|Wl|Wh]^T, BK=64,
// z-outermost block order.  hr: vote-gated defer-max softmax (no per-iter shuffles).
// == exact revert to the round-12 best configuration (641.7 us) ==

#define S_LEN 4096
#define NBLK  128
#define BHT   48
#define HD    64

typedef __attribute__((ext_vector_type(8))) short bf16x8;
typedef __attribute__((ext_vector_type(4))) float f32x4;
typedef unsigned short u16;
typedef unsigned int   u32;
typedef unsigned long long u64;

__device__ __forceinline__ u16 bf16rne(float x) {
    u32 u = __float_as_uint(x);
    u32 r = u + 0x7FFFu + ((u >> 16) & 1u);
    return (u16)(r >> 16);
}
__device__ __forceinline__ float b2f(u16 h) {
    return __uint_as_float((u32)h << 16);
}

__device__ __forceinline__ void gload_lds16(const void* g, void* l) {
    __builtin_amdgcn_global_load_lds((const __attribute__((address_space(1))) void*)g,
                                     (__attribute__((address_space(3))) void*)l, 16, 0, 0);
}

// ---------------------------------------------------------------------------
// 0) fused split: f32 -> bf16 hi/lo planes for X and all three W matrices.
// ---------------------------------------------------------------------------
#define NX8 (16384 * 768 / 8)
#define NW8 (768 * 768 / 8)

__global__ __launch_bounds__(256) void split_all(
    const float* __restrict__ X,
    const float* __restrict__ Wq, const float* __restrict__ Wk, const float* __restrict__ Wv,
    u16* __restrict__ Xh, u16* __restrict__ Xl,
    u16* __restrict__ Wh, u16* __restrict__ Wl)
{
    int i = blockIdx.x * 256 + threadIdx.x;
    if (i >= NX8 + 3 * NW8) return;
    const float* src; u16* dh; u16* dl; size_t off8;
    if (i < NX8) { src = X; dh = Xh; dl = Xl; off8 = i; }
    else {
        int j = i - NX8;
        int w = j / NW8, r = j - w * NW8;
        src = (w == 0) ? Wq : (w == 1) ? Wk : Wv;
        dh = Wh + (size_t)w * 768 * 768;
        dl = Wl + (size_t)w * 768 * 768;
        off8 = r;
    }
    const float4* xp = (const float4*)src + off8 * 2;
    float4 a = xp[0], b = xp[1];
    float xs[8] = {a.x, a.y, a.z, a.w, b.x, b.y, b.z, b.w};
    bf16x8 vh, vl;
    #pragma unroll
    for (int j = 0; j < 8; ++j) {
        u16 hh = bf16rne(xs[j]);
        float hf = b2f(hh);
        vh[j] = (short)hh;
        vl[j] = (short)bf16rne(xs[j] - hf);
    }
    *(bf16x8*)&dh[off8 * 8] = vh;
    *(bf16x8*)&dl[off8 * 8] = vl;
}

// ---------------------------------------------------------------------------
// 1) QKV projection: single K=2304 concat GEMM, BK=64 (two 32-k halves per
//    barrier pair).  128x128 tile, 4 waves.  z-outermost logical order.
// ---------------------------------------------------------------------------
__global__ __launch_bounds__(256, 3) void qkv_mfma(
    const u16* __restrict__ Xh, const u16* __restrict__ Xl,
    const u16* __restrict__ Wh, const u16* __restrict__ Wl,   // [3][768][768]
    const float* __restrict__ bq, const float* __restrict__ bk, const float* __restrict__ bv,
    const float* __restrict__ am,
    u16* __restrict__ Qh, u16* __restrict__ Ql,
    u16* __restrict__ Kh, u16* __restrict__ Kl,
    u16* __restrict__ Vth, u16* __restrict__ Vtl)
{
    const int wg = blockIdx.x;                       // 2304 = 3 z x 128 mt x 6 nt
    const int logical = (wg & 7) * 288 + (wg >> 3);  // XCD-chunked (2304 % 8 == 0)
    const int z   = logical / 768;                   // z outermost: one W set per L2 window
    const int idx = logical - z * 768;
    const int mt  = idx / 6;
    const int nt  = idx - mt * 6;

    const float* bias = (z == 0) ? bq : (z == 1) ? bk : bv;
    const u16* Wzh = Wh + (size_t)z * 768 * 768;
    const u16* Wzl = Wl + (size_t)z * 768 * 768;
    const int m0 = mt * 128, n0 = nt * 128;

    __shared__ char smem[32768];     // A 0..16383 (16 subtiles), B 16384..32767
    const int tid  = threadIdx.x;
    const int lane = tid & 63;
    const int w    = tid >> 6;                    // 4 waves, 2m x 2n
    const int wm   = (w >> 1) * 64, wn = (w & 1) * 64;

    const int rbase = (w < 2) ? m0 : n0;
    const int sub0  = (w & 1) * 4;                // which 4 row-subtiles this wave stages
    char* ldsdst    = (w < 2) ? smem : (smem + 16384);
    const int srow = lane >> 2;                       // 0..15
    const int scg  = (lane & 3) ^ ((lane >> 3) & 3);  // 0..3 (16B colgroup)
    const int tslot = (lane & 15) * 4 + ((lane >> 4) ^ ((lane >> 1) & 3));

    f32x4 acc[4][4];
    #pragma unroll
    for (int i = 0; i < 4; ++i)
        #pragma unroll
        for (int j = 0; j < 4; ++j) acc[i][j] = (f32x4){0.f, 0.f, 0.f, 0.f};

    for (int k0 = 0; k0 < 2304; k0 += 64) {
        const u16* srcA = (k0 < 1536) ? Xh : Xl;
        const u16* srcB = (k0 < 768) ? Wzh : ((k0 < 1536) ? Wzl : Wzh);
        const int  kk   = (k0 < 768) ? k0 : ((k0 < 1536) ? (k0 - 768) : (k0 - 1536));
        const u16* src  = (w < 2) ? srcA : srcB;
        __syncthreads();                 // previous iteration's ds_reads done
        #pragma unroll
        for (int h = 0; h < 2; ++h)
            #pragma unroll
            for (int i = 0; i < 4; ++i) {
                int sub = sub0 + i;
                const u16* g = src + (size_t)(rbase + sub * 16 + srow) * 768
                                   + (kk + h * 32 + scg * 8);
                gload_lds16(g, ldsdst + (h * 8 + sub) * 1024);
            }
        __syncthreads();                 // vmcnt(0) drained by compiler before barrier

        #pragma unroll
        for (int h = 0; h < 2; ++h) {
            bf16x8 af[4], bf[4];
            #pragma unroll
            for (int f = 0; f < 4; ++f) {
                af[f] = *(const bf16x8*)&smem[(h * 8 + (w >> 1) * 4 + f) * 1024 + tslot * 16];
                bf[f] = *(const bf16x8*)&smem[16384 + (h * 8 + (w & 1) * 4 + f) * 1024 + tslot * 16];
            }
            #pragma unroll
            for (int i = 0; i < 4; ++i)
                #pragma unroll
                for (int j = 0; j < 4; ++j)
                    acc[i][j] = __builtin_amdgcn_mfma_f32_16x16x32_bf16(af[i], bf[j], acc[i][j], 0, 0, 0);
        }
    }

    // epilogue: C/D layout col=lane&15, row=(lane>>4)*4+reg
    if (z < 2) {
        u16* Ph = (z == 0) ? Qh : Kh;
        u16* Pl = (z == 0) ? Ql : Kl;
        const float qscale = (z == 0) ? 0.125f : 1.0f;
        #pragma unroll
        for (int i = 0; i < 4; ++i) {
            #pragma unroll
            for (int j = 0; j < 4; ++j) {
                int col = n0 + wn + j * 16 + (lane & 15);
                int h = col >> 6, d = col & 63;
                float bsv = bias[col];
                #pragma unroll
                for (int r = 0; r < 4; ++r) {
                    int row = m0 + wm + i * 16 + (lane >> 4) * 4 + r;
                    int b = row >> 12, s = row & 4095;
                    float mv = 1.0f + am[row] * 1e-4f;
                    float e = (acc[i][j][r] + bsv) * mv * qscale;
                    u16 hh = bf16rne(e);
                    u16 ll = bf16rne(e - b2f(hh));
                    size_t a = (((size_t)(b * 12 + h)) * S_LEN + s) * HD + d;
                    Ph[a] = hh; Pl[a] = ll;
                }
            }
        }
    } else {
        // V: transpose to [bh][d][s], 4 passes of 64d x 64s through LDS
        u32* buf = (u32*)smem;           // [64][66]
        const int bb = m0 >> 12;
        #pragma unroll
        for (int p = 0; p < 4; ++p) {
            const int hh_ = p & 1;       // head half (col half)
            const int rh  = p >> 1;      // row half
            __syncthreads();
            if (((w & 1) == hh_) && ((w >> 1) == rh)) {
                #pragma unroll
                for (int i = 0; i < 4; ++i) {
                    #pragma unroll
                    for (int j = 0; j < 4; ++j) {
                        int d_local = j * 16 + (lane & 15);
                        int col = n0 + hh_ * 64 + d_local;
                        float bsv = bias[col];
                        #pragma unroll
                        for (int r = 0; r < 4; ++r) {
                            int s_local = i * 16 + (lane >> 4) * 4 + r;
                            float mv = 1.0f + am[m0 + rh * 64 + s_local] * 1e-4f;
                            float e = (acc[i][j][r] + bsv) * mv;
                            u16 h16 = bf16rne(e);
                            u16 l16 = bf16rne(e - b2f(h16));
                            buf[d_local * 66 + s_local] = ((u32)h16 << 16) | (u32)l16;
                        }
                    }
                }
            }
            __syncthreads();
            int d_local = tid >> 2;
            int s_chunk = (tid & 3) * 16;
            int head = (n0 >> 6) + hh_;
            size_t ob = (((size_t)(bb * 12 + head)) * HD + d_local) * S_LEN
                        + (m0 & 4095) + rh * 64 + s_chunk;
            #pragma unroll
            for (int gq = 0; gq < 2; ++gq) {
                bf16x8 vh8, vl8;
                #pragma unroll
                for (int t = 0; t < 8; ++t) {
                    u32 pk = buf[d_local * 66 + s_chunk + gq * 8 + t];
                    vh8[t] = (short)(pk >> 16);
                    vl8[t] = (short)(pk & 0xFFFF);
                }
                *(bf16x8*)&Vth[ob + gq * 8] = vh8;
                *(bf16x8*)&Vtl[ob + gq * 8] = vl8;
            }
        }
    }
}

// ---------------------------------------------------------------------------
// 2) f64 selection path: mask-weighted block sums of hidden states.
// ---------------------------------------------------------------------------
__global__ __launch_bounds__(256) void hsum_kernel(
    const float* __restrict__ X, const float* __restrict__ am,
    double* __restrict__ hsum, double* __restrict__ tcd)
{
    int blk = blockIdx.x & 127, b = blockIdx.x >> 7;
    int tid = threadIdx.x;
    const float* xb  = X  + ((size_t)(b * S_LEN + blk * 32)) * 768;
    const float* amb = am + b * S_LEN + blk * 32;
    for (int d = tid; d < 768; d += 256) {
        double s = 0.0;
        for (int t = 0; t < 32; ++t)
            s += (double)xb[(size_t)t * 768 + d] * (1.0 + (double)amb[t] * 1e-4);
        hsum[(size_t)blockIdx.x * 768 + d] = s;
    }
    if (tid == 0) {
        double t = 0.0;
        for (int i = 0; i < 32; ++i) t += 1.0 + (double)amb[i] * 1e-4;
        tcd[blockIdx.x] = t;
    }
}

// ---------------------------------------------------------------------------
// 3) qhat/khat (f64)
// ---------------------------------------------------------------------------
__global__ __launch_bounds__(256) void ghat_kernel(
    const double* __restrict__ hsum,
    const float* __restrict__ Wq, const float* __restrict__ Wk,
    const float* __restrict__ bq, const float* __restrict__ bk,
    const double* __restrict__ tcd,
    double* __restrict__ qhat, double* __restrict__ khat)
{
    const float* W; const float* bias; double* outp;
    if (blockIdx.z == 0) { W = Wq; bias = bq; outp = qhat; }
    else                 { W = Wk; bias = bk; outp = khat; }
    const int n0 = blockIdx.x * 64, m0 = blockIdx.y * 64;
    __shared__ double As[16][72];
    __shared__ float  Bs[16][72];
    const int tid = threadIdx.x;
    const int tx = tid & 15, ty = tid >> 4;
    double acc[4][4] = {};
    const int lr = tid >> 2, lc = (tid & 3) * 4;
    for (int k0 = 0; k0 < 768; k0 += 16) {
        double a0 = hsum[(size_t)(m0 + lr) * 768 + k0 + lc + 0];
        double a1 = hsum[(size_t)(m0 + lr) * 768 + k0 + lc + 1];
        double a2 = hsum[(size_t)(m0 + lr) * 768 + k0 + lc + 2];
        double a3 = hsum[(size_t)(m0 + lr) * 768 + k0 + lc + 3];
        float4 bv = *(const float4*)&W[(size_t)(n0 + lr) * 768 + k0 + lc];
        __syncthreads();
        As[lc+0][lr] = a0; As[lc+1][lr] = a1; As[lc+2][lr] = a2; As[lc+3][lr] = a3;
        Bs[lc+0][lr] = bv.x; Bs[lc+1][lr] = bv.y; Bs[lc+2][lr] = bv.z; Bs[lc+3][lr] = bv.w;
        __syncthreads();
        #pragma unroll
        for (int kk = 0; kk < 16; ++kk) {
            double af[4]; float bf[4];
            #pragma unroll
            for (int i = 0; i < 4; ++i) af[i] = As[kk][ty*4+i];
            #pragma unroll
            for (int j = 0; j < 4; ++j) bf[j] = Bs[kk][tx*4+j];
            #pragma unroll
            for (int i = 0; i < 4; ++i)
                #pragma unroll
                for (int j = 0; j < 4; ++j)
                    acc[i][j] += af[i] * (double)bf[j];
        }
    }
    #pragma unroll
    for (int i = 0; i < 4; ++i) {
        int m = m0 + ty*4 + i;
        int b = m >> 7, blk = m & 127;
        double t = tcd[m];
        #pragma unroll
        for (int j = 0; j < 4; ++j) {
            int o = n0 + tx*4 + j;
            int h = o >> 6, d = o & 63;
            outp[(((size_t)(b*12 + h)) * NBLK + blk) * HD + d] = (acc[i][j] + t * (double)bias[o]) / (t + 1e-6);
        }
    }
}

// ---------------------------------------------------------------------------
// 4) low-res logits (f64), 4 query rows per block, fused u64 selection keys.
// ---------------------------------------------------------------------------
__global__ __launch_bounds__(128) void lrl_kernel(
    const double* __restrict__ qhat, const double* __restrict__ khat,
    const double* __restrict__ tcd,
    double* __restrict__ lrl, double* __restrict__ rmax,
    u64* __restrict__ keys)
{
    const int q0 = blockIdx.x * 4, bh = blockIdx.y;
    const int b = bh / 12;
    __shared__ double qr[4][64];
    __shared__ double red[4][128];
    const int tid = threadIdx.x;
    if (tid < 64) {
        #pragma unroll
        for (int qq = 0; qq < 4; ++qq)
            qr[qq][tid] = qhat[(((size_t)bh) * NBLK + q0 + qq) * HD + tid];
    }
    __syncthreads();
    const double* kr = &khat[(((size_t)bh) * NBLK + tid) * HD];
    double s[4] = {0.0, 0.0, 0.0, 0.0};
    for (int d = 0; d < 64; d += 2) {
        double2 kv2 = *(const double2*)&kr[d];
        #pragma unroll
        for (int qq = 0; qq < 4; ++qq)
            s[qq] += qr[qq][d] * kv2.x + qr[qq][d + 1] * kv2.y;
    }
    #pragma unroll
    for (int qq = 0; qq < 4; ++qq) { s[qq] *= 0.125; red[qq][tid] = s[qq]; }
    __syncthreads();
    for (int off = 64; off > 0; off >>= 1) {
        if (tid < off) {
            #pragma unroll
            for (int qq = 0; qq < 4; ++qq)
                red[qq][tid] = fmax(red[qq][tid], red[qq][tid + off]);
        }
        __syncthreads();
    }
    const double tck = tcd[b * NBLK + tid];
    #pragma unroll
    for (int qq = 0; qq < 4; ++qq) {
        const int qi = q0 + qq;
        const double rmaxv = red[qq][0];
        double pen = (tcd[b * NBLK + qi] * tck < 0.5) ? 1e4 : 0.0;
        const double lv = s[qq] - pen;
        lrl[(size_t)bh * (NBLK*NBLK) + (size_t)qi * NBLK + tid] = lv;
        if (tid == 0) rmax[bh * NBLK + qi] = rmaxv;
        int dd = qi - tid; if (dd < 0) dd = -dd;
        double ks_ = lv - rmaxv + ((dd <= 1) ? 5000.0 : 0.0);
        u64 u = (u64)__double_as_longlong(ks_);
        u = (u >> 63) ? ~u : (u | 0x8000000000000000ULL);
        keys[(size_t)bh * (NBLK*NBLK) + (size_t)qi * NBLK + tid] = u;
    }
}

// ---------------------------------------------------------------------------
// 5) v_hat (f32) + tc (from hsum's f64 tcd).
// ---------------------------------------------------------------------------
__global__ __launch_bounds__(64) void vhat_kernel(
    const u16* __restrict__ Vth, const u16* __restrict__ Vtl,
    const double* __restrict__ tcd,
    float* __restrict__ vhat, float* __restrict__ tcf)
{
    const int d = blockIdx.x, bh = blockIdx.y;
    const int b = bh / 12;
    const int l = threadIdx.x;
    const u16* ph = Vth + ((size_t)bh * HD + d) * S_LEN + l * 64;
    const u16* pl = Vtl + ((size_t)bh * HD + d) * S_LEN + l * 64;
    float s[2] = {0.f, 0.f};
    #pragma unroll
    for (int g = 0; g < 2; ++g) {
        #pragma unroll
        for (int v = 0; v < 4; ++v) {
            bf16x8 vh = *(const bf16x8*)&ph[g * 32 + v * 8];
            bf16x8 vl = *(const bf16x8*)&pl[g * 32 + v * 8];
            #pragma unroll
            for (int j = 0; j < 8; ++j)
                s[g] += b2f((u16)vh[j]) + b2f((u16)vl[j]);
        }
    }
    #pragma unroll
    for (int g = 0; g < 2; ++g) {
        int blk = l * 2 + g;
        float tc = (float)tcd[b * NBLK + blk];
        vhat[(((size_t)bh) * NBLK + blk) * HD + d] = s[g] / (tc + 1e-6f);
        if (d == 0) tcf[bh * NBLK + blk] = tc;
    }
}

// ---------------------------------------------------------------------------
// 6) top-512 radix select (per-wave privatized histograms) + per-row lists.
// ---------------------------------------------------------------------------
__global__ __launch_bounds__(256) void topk_kernel(
    const u64* __restrict__ keys,
    double* __restrict__ th64, int* __restrict__ cnt, unsigned char* __restrict__ lists,
    int* __restrict__ eqbuf, int* __restrict__ eqcnt)
{
    const int bh = blockIdx.x, tid = threadIdx.x;
    const int wid = tid >> 6;
    __shared__ int hist[4][256];
    __shared__ u64 s_pref;
    __shared__ int s_K;
    const u64* kp = keys + (size_t)bh * (NBLK*NBLK);
    if (tid < 128) cnt[bh * NBLK + tid] = 0;
    if (tid == 0) eqcnt[bh] = 0;

    u64 pref = 0, pmask = 0;
    int K = 512;
    for (int by = 7; by >= 0; --by) {
        #pragma unroll
        for (int w = 0; w < 4; ++w) hist[w][tid] = 0;
        __syncthreads();
        for (int i = tid; i < NBLK*NBLK; i += 256) {
            u64 u = kp[i];
            if ((u & pmask) == pref)
                atomicAdd(&hist[wid][(int)((u >> (by*8)) & 255)], 1);
        }
        __syncthreads();
        int tot = hist[0][tid] + hist[1][tid] + hist[2][tid] + hist[3][tid];
        hist[0][tid] = tot;
        __syncthreads();
        if (tid == 0) {
            int c = 0, bsel = 0;
            for (int x = 255; x >= 0; --x) {
                if (c + hist[0][x] >= K) { bsel = x; break; }
                c += hist[0][x];
            }
            s_pref = pref | ((u64)bsel << (by*8));
            s_K = K - c;
        }
        __syncthreads();
        pref = s_pref; K = s_K;
        pmask |= 0xFFULL << (by*8);
        __syncthreads();
    }
    const u64 tkey = pref;
    int n_take = K;
    if (tid == 0) {
        u64 u = (tkey & 0x8000000000000000ULL) ? (tkey ^ 0x8000000000000000ULL) : ~tkey;
        th64[bh] = __longlong_as_double((long long)u);
    }
    for (int i = tid; i < NBLK*NBLK; i += 256) {
        u64 u = kp[i];
        if (u > tkey) {
            int qi = i >> 7, ki = i & 127;
            int pos = atomicAdd(&cnt[bh * NBLK + qi], 1);
            lists[(((size_t)bh) * NBLK + qi) * NBLK + pos] = (unsigned char)ki;
        } else if (u == tkey) {
            int e = atomicAdd(&eqcnt[bh], 1);
            if (e < 512) eqbuf[bh * 512 + e] = i;
        }
    }
    __syncthreads();
    if (tid == 0) {
        int ne = eqcnt[bh]; if (ne > 512) ne = 512;
        int* eb = &eqbuf[bh * 512];
        for (int a = 1; a < ne; ++a) {
            int v = eb[a]; int x = a - 1;
            while (x >= 0 && eb[x] > v) { eb[x+1] = eb[x]; --x; }
            eb[x+1] = v;
        }
        if (n_take > ne) n_take = ne;
        for (int j = 0; j < n_take; ++j) {
            int i = eb[j]; int qi = i >> 7, ki = i & 127;
            int pos = cnt[bh * NBLK + qi]++;
            lists[(((size_t)bh) * NBLK + qi) * NBLK + pos] = (unsigned char)ki;
        }
    }
    __syncthreads();
    if (tid < 128) {
        int n = cnt[bh * NBLK + tid];
        unsigned char* l = &lists[(((size_t)bh) * NBLK + tid) * NBLK];
        for (int a = 1; a < n; ++a) {
            unsigned char v = l[a]; int x = a - 1;
            while (x >= 0 && l[x] > v) { l[x+1] = l[x]; --x; }
            l[x+1] = v;
        }
    }
}

// ---------------------------------------------------------------------------
// 7) High-res sparse attention: split-bf16 MFMA, vote-gated defer-max softmax
//    (no cross-lane ops in the common path; l reduced once after the loop),
//    P double-buffer -> 1 barrier/iter.  One wave per (bh, qi).
// ---------------------------------------------------------------------------
__global__ __launch_bounds__(64) void hr_mfma(
    const u16* __restrict__ Qh, const u16* __restrict__ Ql,
    const u16* __restrict__ Kh, const u16* __restrict__ Kl,
    const u16* __restrict__ Vth, const u16* __restrict__ Vtl,
    const double* __restrict__ lrl64, const double* __restrict__ rmax64, const double* __restrict__ th64,
    const int* __restrict__ cnt, const unsigned char* __restrict__ lists,
    const float* __restrict__ vhat, const float* __restrict__ tcf,
    const float* __restrict__ am, float* __restrict__ out)
{
    const int qi = blockIdx.x, bh = blockIdx.y;
    const int l  = threadIdx.x;
    const int lr_ = l & 15, lg = l >> 4;
    __shared__ u16 PhL[2][32][40];    // double-buffered P tiles
    __shared__ u16 PlL[2][32][40];
    __shared__ float wlr[128];
    __shared__ float lrvec[64];

    bf16x8 qfh[2][2], qfl[2][2];
    #pragma unroll
    for (int qs = 0; qs < 2; ++qs)
        #pragma unroll
        for (int ds = 0; ds < 2; ++ds) {
            size_t a = (((size_t)bh) * S_LEN + qi * 32 + qs * 16 + lr_) * HD + ds * 32 + lg * 8;
            qfh[qs][ds] = *(const bf16x8*)&Qh[a];
            qfl[qs][ds] = *(const bf16x8*)&Ql[a];
        }

    float m_run[2][4], l_part[2][4];
    f32x4 oacc[2][4];
    #pragma unroll
    for (int qs = 0; qs < 2; ++qs) {
        #pragma unroll
        for (int r = 0; r < 4; ++r) { m_run[qs][r] = -1e30f; l_part[qs][r] = 0.f; }
        #pragma unroll
        for (int dv = 0; dv < 4; ++dv) oacc[qs][dv] = (f32x4){0.f, 0.f, 0.f, 0.f};
    }

    const int c = cnt[bh * NBLK + qi];
    const unsigned char* ml = &lists[(((size_t)bh) * NBLK + qi) * NBLK];

    int pb = 0;
    for (int bi = 0; bi < c; ++bi) {
        const int ki = ml[bi];
        f32x4 S[2][2];
        #pragma unroll
        for (int qs = 0; qs < 2; ++qs)
            #pragma unroll
            for (int ks = 0; ks < 2; ++ks) S[qs][ks] = (f32x4){0.f, 0.f, 0.f, 0.f};
        #pragma unroll
        for (int ds = 0; ds < 2; ++ds)
            #pragma unroll
            for (int ks = 0; ks < 2; ++ks) {
                size_t a = (((size_t)bh) * S_LEN + ki * 32 + ks * 16 + lr_) * HD + ds * 32 + lg * 8;
                bf16x8 kh = *(const bf16x8*)&Kh[a];
                bf16x8 kl = *(const bf16x8*)&Kl[a];
                S[0][ks] = __builtin_amdgcn_mfma_f32_16x16x32_bf16(qfh[0][ds], kh, S[0][ks], 0, 0, 0);
                S[1][ks] = __builtin_amdgcn_mfma_f32_16x16x32_bf16(qfh[1][ds], kh, S[1][ks], 0, 0, 0);
                S[0][ks] = __builtin_amdgcn_mfma_f32_16x16x32_bf16(qfh[0][ds], kl, S[0][ks], 0, 0, 0);
                S[1][ks] = __builtin_amdgcn_mfma_f32_16x16x32_bf16(qfh[1][ds], kl, S[1][ks], 0, 0, 0);
                S[0][ks] = __builtin_amdgcn_mfma_f32_16x16x32_bf16(qfl[0][ds], kh, S[0][ks], 0, 0, 0);
                S[1][ks] = __builtin_amdgcn_mfma_f32_16x16x32_bf16(qfl[1][ds], kh, S[1][ks], 0, 0, 0);
            }
        // vote-gated defer-max (exact for mask==1: combine invariant to lagged m)
        float lmax[2][4];
        bool need = false;
        #pragma unroll
        for (int qs = 0; qs < 2; ++qs)
            #pragma unroll
            for (int r = 0; r < 4; ++r) {
                lmax[qs][r] = fmaxf(S[qs][0][r], S[qs][1][r]);
                need |= (lmax[qs][r] > m_run[qs][r] + 8.f);
            }
        if (__any(need)) {   // rare: full per-row max reduce + rescale
            #pragma unroll
            for (int qs = 0; qs < 2; ++qs)
                #pragma unroll
                for (int r = 0; r < 4; ++r) {
                    float bm = lmax[qs][r];
                    bm = fmaxf(bm, __shfl_xor(bm, 1));
                    bm = fmaxf(bm, __shfl_xor(bm, 2));
                    bm = fmaxf(bm, __shfl_xor(bm, 4));
                    bm = fmaxf(bm, __shfl_xor(bm, 8));
                    float mn = fmaxf(m_run[qs][r], bm);
                    float sc = __expf(m_run[qs][r] - mn);
                    m_run[qs][r] = mn;
                    l_part[qs][r] *= sc;
                    #pragma unroll
                    for (int dv = 0; dv < 4; ++dv) oacc[qs][dv][r] *= sc;
                }
        }
        #pragma unroll
        for (int qs = 0; qs < 2; ++qs)
            #pragma unroll
            for (int r = 0; r < 4; ++r) {
                float p0 = __expf(S[qs][0][r] - m_run[qs][r]);
                float p1 = __expf(S[qs][1][r] - m_run[qs][r]);
                l_part[qs][r] += p0 + p1;          // per-lane partial; reduced after loop
                int row = qs * 16 + lg * 4 + r;
                u16 h0 = bf16rne(p0); u16 lo0 = bf16rne(p0 - b2f(h0));
                u16 h1 = bf16rne(p1); u16 lo1 = bf16rne(p1 - b2f(h1));
                PhL[pb][row][lr_]      = h0;  PlL[pb][row][lr_]      = lo0;
                PhL[pb][row][16 + lr_] = h1;  PlL[pb][row][16 + lr_] = lo1;
            }
        __syncthreads();   // P[pb] visible; previous buffer's readers already passed here
        bf16x8 pah[2], pal[2];
        #pragma unroll
        for (int qs = 0; qs < 2; ++qs) {
            pah[qs] = *(const bf16x8*)&PhL[pb][qs * 16 + lr_][lg * 8];
            pal[qs] = *(const bf16x8*)&PlL[pb][qs * 16 + lr_][lg * 8];
        }
        #pragma unroll
        for (int dv = 0; dv < 4; ++dv) {
            size_t a = (((size_t)bh) * HD + dv * 16 + lr_) * S_LEN + ki * 32 + lg * 8;
            bf16x8 vh = *(const bf16x8*)&Vth[a];
            bf16x8 vl = *(const bf16x8*)&Vtl[a];
            #pragma unroll
            for (int qs = 0; qs < 2; ++qs) {
                oacc[qs][dv] = __builtin_amdgcn_mfma_f32_16x16x32_bf16(pah[qs], vh, oacc[qs][dv], 0, 0, 0);
                oacc[qs][dv] = __builtin_amdgcn_mfma_f32_16x16x32_bf16(pah[qs], vl, oacc[qs][dv], 0, 0, 0);
                oacc[qs][dv] = __builtin_amdgcn_mfma_f32_16x16x32_bf16(pal[qs], vh, oacc[qs][dv], 0, 0, 0);
            }
        }
        pb ^= 1;           // no trailing barrier: next iter writes the other buffer
    }
    __syncthreads();

    // final l reduction (once): sum l_part across the 16 k-lanes of each row
    float l_run[2][4];
    #pragma unroll
    for (int qs = 0; qs < 2; ++qs)
        #pragma unroll
        for (int r = 0; r < 4; ++r) {
            float rs = l_part[qs][r];
            rs += __shfl_xor(rs, 1);
            rs += __shfl_xor(rs, 2);
            rs += __shfl_xor(rs, 4);
            rs += __shfl_xor(rs, 8);
            l_run[qs][r] = rs;
        }

    // ---- low-res branch ----
    const double thv  = th64[bh];
    const double rm64 = rmax64[bh * NBLK + qi];
    const int b = bh / 12, h = bh % 12;
    float wpair = 0.f;
    #pragma unroll
    for (int half = 0; half < 2; ++half) {
        int m = l + half * 64;
        double lv = lrl64[(size_t)bh * (NBLK*NBLK) + (size_t)qi * NBLK + m];
        int dd = qi - m; if (dd < 0) dd = -dd;
        double s = lv - rm64 + ((dd <= 1) ? 5000.0 : 0.0);
        float wv;
        if (s >= thv) wv = 0.f;
        else          wv = (float)exp(lv - rm64) * tcf[bh * NBLK + m];
        wlr[m] = wv;
        wpair += wv;
    }
    float s_lrn = wpair;
    s_lrn += __shfl_xor(s_lrn, 1);
    s_lrn += __shfl_xor(s_lrn, 2);
    s_lrn += __shfl_xor(s_lrn, 4);
    s_lrn += __shfl_xor(s_lrn, 8);
    s_lrn += __shfl_xor(s_lrn, 16);
    s_lrn += __shfl_xor(s_lrn, 32);
    __syncthreads();
    float a_ = 0.f;
    for (int m = 0; m < 128; ++m)
        a_ += wlr[m] * vhat[(((size_t)bh) * NBLK + m) * HD + l];
    lrvec[l] = a_;
    __syncthreads();
    float lv4[4];
    #pragma unroll
    for (int dv = 0; dv < 4; ++dv) lv4[dv] = lrvec[dv * 16 + lr_];

    // ---- combine & write ----
    const float rmf = (float)rm64;
    #pragma unroll
    for (int qs = 0; qs < 2; ++qs)
        #pragma unroll
        for (int r = 0; r < 4; ++r) {
            int q = qs * 16 + lg * 4 + r;
            int srow = qi * 32 + q;
            float mv = 1.0f + am[b * S_LEN + srow] * 1e-4f;
            float logc = (rmf - m_run[qs][r]) * mv;
            float lrc = (logc <= 0.f) ? expf(logc)  : 1.0f;
            float hrc = (logc >  0.f) ? expf(-logc) : 1.0f;
            float den = l_run[qs][r] * hrc + s_lrn * lrc + 1e-6f;
            float scd = mv / den;
            size_t ob = ((size_t)(b * S_LEN + srow)) * 768 + h * HD;
            #pragma unroll
            for (int dv = 0; dv < 4; ++dv)
                out[ob + dv * 16 + lr_] = (oacc[qs][dv][r] * hrc + lv4[dv] * lrc) * scd;
        }
}

// ---------------------------------------------------------------------------
extern "C" void kernel_launch(void* const* d_in, const int* in_sizes, int n_in,
                              void* d_out, int out_size, void* d_ws, size_t ws_size,
                              hipStream_t stream)
{
    (void)in_sizes; (void)n_in; (void)out_size; (void)ws_size;
    const float* X  = (const float*)d_in[0];
    const float* am = (const float*)d_in[1];
    const float* Wq = (const float*)d_in[2];
    const float* bq = (const float*)d_in[3];
    const float* Wk = (const float*)d_in[4];
    const float* bk = (const float*)d_in[5];
    const float* Wv = (const float*)d_in[6];
    const float* bv = (const float*)d_in[7];
    float* out = (float*)d_out;

    char* p = (char*)d_ws;
    const size_t PLANE = (size_t)BHT * S_LEN * HD * 2;
    u16* Qh  = (u16*)p; p += PLANE;
    u16* Ql  = (u16*)p; p += PLANE;
    u16* Kh  = (u16*)p; p += PLANE;
    u16* Kl  = (u16*)p; p += PLANE;
    u16* Vth = (u16*)p; p += PLANE;
    u16* Vtl = (u16*)p; p += PLANE;
    char* region = p;

    // ---- phase A layout (dead after qkv_mfma): bf16 splits of X, W ----
    char* pa = region;
    u16* Xh = (u16*)pa; pa += (size_t)16384 * 768 * 2;
    u16* Xl = (u16*)pa; pa += (size_t)16384 * 768 * 2;
    u16* Wh = (u16*)pa; pa += (size_t)3 * 768 * 768 * 2;
    u16* Wl = (u16*)pa; pa += (size_t)3 * 768 * 768 * 2;

    // ---- phase B/C layout (reuses phase A region) ----
    char* pb = region;
    double* hsum   = (double*)pb; pb += (size_t)512 * 768 * 8;
    double* tcd    = (double*)pb; pb += (size_t)512 * 8;
    double* qhat64 = (double*)pb; pb += (size_t)BHT * NBLK * HD * 8;
    double* khat64 = (double*)pb; pb += (size_t)BHT * NBLK * HD * 8;
    double* lrl64  = (double*)pb; pb += (size_t)BHT * NBLK * NBLK * 8;
    double* rmax64 = (double*)pb; pb += (size_t)BHT * NBLK * 8;
    double* th64   = (double*)pb; pb += (size_t)BHT * 8;
    u64* keys   = (u64*)pb;   pb += (size_t)BHT * NBLK * NBLK * 8;
    float* vhat = (float*)pb; pb += (size_t)BHT * NBLK * HD * 4;
    float* tcf  = (float*)pb; pb += (size_t)BHT * NBLK * 4;
    int* cnt    = (int*)pb;   pb += (size_t)BHT * NBLK * 4;
    int* eqbuf  = (int*)pb;   pb += (size_t)BHT * 512 * 4;
    int* eqcnt  = (int*)pb;   pb += (size_t)BHT * 4;
    unsigned char* lists = (unsigned char*)pb; pb += (size_t)BHT * NBLK * NBLK;

    // phase A: fused split + MFMA QKV projection -> bf16 planes
    split_all<<<7008, 256, 0, stream>>>(X, Wq, Wk, Wv, Xh, Xl, Wh, Wl);
    qkv_mfma<<<2304, 256, 0, stream>>>(Xh, Xl, Wh, Wl, bq, bk, bv, am,
                                       Qh, Ql, Kh, Kl, Vth, Vtl);

    // phase B: f64 selection path (region reused — stream order serializes)
    hsum_kernel<<<512, 256, 0, stream>>>(X, am, hsum, tcd);
    ghat_kernel<<<dim3(12, 8, 2), 256, 0, stream>>>(hsum, Wq, Wk, bq, bk, tcd, qhat64, khat64);
    lrl_kernel<<<dim3(32, BHT), 128, 0, stream>>>(qhat64, khat64, tcd, lrl64, rmax64, keys);
    vhat_kernel<<<dim3(64, BHT), 64, 0, stream>>>(Vth, Vtl, tcd, vhat, tcf);
    topk_kernel<<<BHT, 256, 0, stream>>>(keys, th64, cnt, lists, eqbuf, eqcnt);

    // phase C: high-res + combine
    hr_mfma<<<dim3(NBLK, BHT), 64, 0, stream>>>(Qh, Ql, Kh, Kl, Vth, Vtl,
                                                lrl64, rmax64, th64,
                                                cnt, lists, vhat, tcf, am, out);
}